// Round 8
// baseline (30.142 us; speedup 1.0000x reference)
//
#include <hip/hip_runtime.h>

#define K_TOTAL 32768
#define R_TOTAL 128
#define A_DIM   16
#define NBUCK   128
#define RHO_STR 20          // rho row padded to 20 floats (80 B, 16B-aligned)

// d_ws layout (bytes):
//   [0,     32768)  LUT    uint4[A_DIM*NBUCK]  bit r => rule r is a candidate
//   [32768, 65536)  rules4 float4[R_TOTAL*A_DIM] = {A, 1/(B-A), D, 1/(D-C)}
//   [65536, 75776)  rhop   float[R_TOTAL*RHO_STR] (col 16 = bias)

// ---------------------------------------------------------------------------
// Kernel 1: build tables. 4096 threads.
//   g < 2048 : fold abcd(r,a) -> rules4 + strided rho copy
//   g >= 2048: LUT entry (dim, bucket): loop 128 rules, conservative
//              interval-vs-widened-bucket intersection test (exact fp:
//              (b±)/128 are exact in fp32).
// ---------------------------------------------------------------------------
__global__ __launch_bounds__(256) void fuzzy_tables(const float* __restrict__ abcd,
                                                    const float* __restrict__ rho,
                                                    uint4* __restrict__ lut,
                                                    float4* __restrict__ rules4,
                                                    float* __restrict__ rhop) {
    int g = blockIdx.x * 256 + threadIdx.x;            // 0..4095
    if (g < R_TOTAL * A_DIM) {
        float4 v = ((const float4*)abcd)[g];
        float v0 = v.x, v1 = v.y, v2 = v.z, v3 = v.w, s;
        s = fminf(v0, v1); v1 = fmaxf(v0, v1); v0 = s;
        s = fminf(v2, v3); v3 = fmaxf(v2, v3); v2 = s;
        s = fminf(v0, v2); v2 = fmaxf(v0, v2); v0 = s;
        s = fminf(v1, v3); v3 = fmaxf(v1, v3); v1 = s;
        s = fminf(v1, v2); v2 = fmaxf(v1, v2); v1 = s;
        // v0<=v1<=v2<=v3
        rules4[g] = make_float4(v0, __builtin_amdgcn_rcpf(v1 - v0),
                                v3, __builtin_amdgcn_rcpf(v3 - v2));
        // rho copy (2176 elements over 2048 threads, strided)
        for (int f = g; f < R_TOTAL * (A_DIM + 1); f += R_TOTAL * A_DIM) {
            int r = f / (A_DIM + 1);
            int c = f - r * (A_DIM + 1);
            rhop[r * RHO_STR + c] = rho[f];
        }
    } else {
        int e = g - R_TOTAL * A_DIM;                   // 0..2047
        int a = e >> 7;                                // dim
        int b = e & (NBUCK - 1);                       // bucket
        float lo = (float)(b - 1) * 0.0078125f;        // widened -1 bucket
        float hi = (float)(b + 2) * 0.0078125f;        // widened +1 bucket
        unsigned m0 = 0, m1 = 0, m2 = 0, m3 = 0;
        for (int r = 0; r < R_TOTAL; ++r) {
            float4 v = ((const float4*)abcd)[(r << 4) + a];
            float amin = fminf(fminf(v.x, v.y), fminf(v.z, v.w));
            float dmax = fmaxf(fmaxf(v.x, v.y), fmaxf(v.z, v.w));
            unsigned hit = (amin <= hi && dmax >= lo) ? 1u : 0u;
            unsigned bit = hit << (r & 31);
            if      (r < 32) m0 |= bit;
            else if (r < 64) m1 |= bit;
            else if (r < 96) m2 |= bit;
            else             m3 |= bit;
        }
        lut[e] = make_uint4(m0, m1, m2, m3);
    }
}

// ---------------------------------------------------------------------------
// Kernel 2: sparse main pass. 256 blocks x 128 threads; thread = one k.
//   Stage 32 KB LUT to LDS (coalesced). Per k: quantize 16 dims, AND the
//   16 candidate masks (-> ~0.07 rules/k), then exact membership + z only
//   for candidates (false positives multiply out to exact 0).
// ---------------------------------------------------------------------------
__global__ __launch_bounds__(128)
void fuzzy_sparse(const float* __restrict__ input,
                  const uint4* __restrict__ lut_g,
                  const float4* __restrict__ rules4,
                  const float* __restrict__ rhop,
                  float* __restrict__ out) {
    __shared__ uint4 lut[A_DIM * NBUCK];               // 32 KB

    const int t = threadIdx.x;
    const int k = blockIdx.x * 128 + t;

    // per-thread x (issue before staging so loads overlap)
    float x[A_DIM];
    {
        const float4* xp = (const float4*)(input + (size_t)k * A_DIM);
        float4 a0 = xp[0], a1 = xp[1], a2 = xp[2], a3 = xp[3];
        x[0]=a0.x;  x[1]=a0.y;  x[2]=a0.z;  x[3]=a0.w;
        x[4]=a1.x;  x[5]=a1.y;  x[6]=a1.z;  x[7]=a1.w;
        x[8]=a2.x;  x[9]=a2.y;  x[10]=a2.z; x[11]=a2.w;
        x[12]=a3.x; x[13]=a3.y; x[14]=a3.z; x[15]=a3.w;
    }

    // stage LUT: 2048 uint4 / 128 threads = 16 coalesced iters
    #pragma unroll
    for (int i = 0; i < 16; ++i) lut[t + i * 128] = lut_g[t + i * 128];
    __syncthreads();

    // AND the 16 per-dim candidate masks
    uint4 mm;
    {
        int b0 = min(NBUCK - 1, (int)(x[0] * (float)NBUCK));
        mm = lut[b0];
        #pragma unroll
        for (int a = 1; a < A_DIM; ++a) {
            int b = min(NBUCK - 1, (int)(x[a] * (float)NBUCK));
            uint4 v = lut[a * NBUCK + b];
            mm.x &= v.x; mm.y &= v.y; mm.z &= v.z; mm.w &= v.w;
        }
    }

    unsigned long long mlo = ((unsigned long long)mm.y << 32) | mm.x;
    unsigned long long mhi = ((unsigned long long)mm.w << 32) | mm.z;

    float num = 0.0f, den = 0.0f;
    while (mlo | mhi) {
        int r;
        if (mlo) { r = __builtin_ctzll(mlo);      mlo &= mlo - 1; }
        else     { r = 64 + __builtin_ctzll(mhi); mhi &= mhi - 1; }

        const float4* __restrict__ rp = rules4 + (r << 4);
        float w = 1.0f;
        #pragma unroll
        for (int a = 0; a < A_DIM; ++a) {
            float4 c   = rp[a];
            float rise = (x[a] - c.x) * c.y;
            float fall = (c.z - x[a]) * c.w;
            w *= __builtin_amdgcn_fmed3f(fminf(rise, fall), 0.0f, 1.0f);
        }
        if (w != 0.0f) {
            const float* __restrict__ rh = rhop + r * RHO_STR;
            float z = rh[A_DIM];
            #pragma unroll
            for (int a = 0; a < A_DIM; ++a) z = fmaf(x[a], rh[a], z);
            num = fmaf(z, w, num);
            den += w;
        }
    }

    out[k] = num * __builtin_amdgcn_rcpf(den + 1e-13f);
}

// ---------------------------------------------------------------------------
extern "C" void kernel_launch(void* const* d_in, const int* in_sizes, int n_in,
                              void* d_out, int out_size, void* d_ws, size_t ws_size,
                              hipStream_t stream) {
    const float* input = (const float*)d_in[0];   // (K, A)    fp32
    const float* abcd  = (const float*)d_in[1];   // (R, A, 4) fp32
    const float* rho   = (const float*)d_in[2];   // (R, A+1)  fp32
    float* out = (float*)d_out;                   // (K,)      fp32

    char* ws = (char*)d_ws;
    uint4*  lut    = (uint4*)(ws);                // 32 KB
    float4* rules4 = (float4*)(ws + 32768);       // 32 KB
    float*  rhop   = (float*)(ws + 65536);        // 10 KB

    fuzzy_tables<<<16, 256, 0, stream>>>(abcd, rho, lut, rules4, rhop);
    fuzzy_sparse<<<K_TOTAL / 128, 128, 0, stream>>>(input, lut, rules4, rhop, out);
}

// Round 9
// 13.517 us; speedup vs baseline: 2.2298x; 2.2298x over previous
//
#include <hip/hip_runtime.h>

#define K_TOTAL 32768
#define R_TOTAL 128
#define A_DIM   16

#define REC 84   // floats per rule record in LDS (336 B, 16B-aligned)
// per-rule LDS record layout (floats):
//   [ 0..31]  stage A (dims 0-7):  IBA[8] | C1[8]=-A*IBA | NIDC[8]=-IDC | C3[8]=D*IDC
//   [32..63]  stage B (dims 8-15): same sub-layout
//   [64..79]  rho[0..15]
//   [80]      bias ; [81..83] pad

typedef float v2f __attribute__((ext_vector_type(2)));

// membership for a dim-pair: rise=x*IBA+C1, fall=x*NIDC+C3, clamp to [0,1]
__device__ __forceinline__ v2f memb_pair(v2f X, const float* rec, int p) {
    v2f iba = *(const v2f*)(rec + 2 * p);
    v2f c1  = *(const v2f*)(rec + 8 + 2 * p);
    v2f nid = *(const v2f*)(rec + 16 + 2 * p);
    v2f c3  = *(const v2f*)(rec + 24 + 2 * p);
    v2f rise = X * iba + c1;     // v_pk_fma_f32
    v2f fall = X * nid + c3;
    v2f M;
    M.x = __builtin_amdgcn_fmed3f(fminf(rise.x, fall.x), 0.0f, 1.0f);
    M.y = __builtin_amdgcn_fmed3f(fminf(rise.y, fall.y), 0.0f, 1.0f);
    return M;
}

// Single fused kernel. 512 blocks x 1024 threads (16 waves; 2 blocks/CU ->
// 32 waves/CU). Block owns 64 k's (lane = k); wave wv owns rules
// [wv*8, wv*8+8). Phase 1: block folds sort+rcp constants into LDS once
// (coalesced global reads). Phase 2: rule constants are wave-uniform LDS
// broadcasts feeding packed-fp32 VALU; early-out after dims 8 / 12; z-dot
// only when some lane survives all 16 dims (~2%). Skips are exact +0.
__global__ __launch_bounds__(1024, 2)
void fuzzy_fused(const float* __restrict__ input,
                 const float* __restrict__ abcd,
                 const float* __restrict__ rho,
                 float* __restrict__ out) {
    __shared__ float tab[R_TOTAL * REC];   // 43008 B
    __shared__ float nsh[16][64];          // 4096 B
    __shared__ float dsh[16][64];          // 4096 B

    const int t     = threadIdx.x;
    const int lane  = t & 63;
    const int wv    = __builtin_amdgcn_readfirstlane(t >> 6);
    const int kbase = blockIdx.x * 64;

    // ---------------- Phase 1: fold constants into LDS ---------------------
    #pragma unroll
    for (int i = 0; i < 2; ++i) {
        int e  = t + i * 1024;                 // (r,a) entry, < 2048
        int r  = e >> 4, a = e & 15, st = a >> 3, ai = a & 7;
        float4 v = ((const float4*)abcd)[e];
        float v0 = v.x, v1 = v.y, v2 = v.z, v3 = v.w, s;
        s = fminf(v0, v1); v1 = fmaxf(v0, v1); v0 = s;
        s = fminf(v2, v3); v3 = fmaxf(v2, v3); v2 = s;
        s = fminf(v0, v2); v2 = fmaxf(v0, v2); v0 = s;
        s = fminf(v1, v3); v3 = fmaxf(v1, v3); v1 = s;
        s = fminf(v1, v2); v2 = fmaxf(v1, v2); v1 = s;
        // v0<=v1<=v2<=v3
        float iba = __builtin_amdgcn_rcpf(v1 - v0);
        float idc = __builtin_amdgcn_rcpf(v3 - v2);
        float* base = tab + r * REC + st * 32;
        base[ai]      =  iba;
        base[8 + ai]  = -v0 * iba;
        base[16 + ai] = -idc;
        base[24 + ai] =  v3 * idc;
    }
    #pragma unroll
    for (int i = 0; i < 3; ++i) {
        int f = t + i * 1024;                  // rho element, < 2176
        if (f < R_TOTAL * (A_DIM + 1)) {
            int r = f / (A_DIM + 1);
            int c = f - r * (A_DIM + 1);
            tab[r * REC + 64 + c] = rho[f];    // c==16 -> bias at [80]
        }
    }

    // per-lane k-point coordinates as 8 pairs (overlaps fold latency)
    v2f X[8];
    {
        const float4* xp = (const float4*)(input + (size_t)(kbase + lane) * A_DIM);
        float4 a0 = xp[0], a1 = xp[1], a2 = xp[2], a3 = xp[3];
        X[0] = (v2f){a0.x, a0.y}; X[1] = (v2f){a0.z, a0.w};
        X[2] = (v2f){a1.x, a1.y}; X[3] = (v2f){a1.z, a1.w};
        X[4] = (v2f){a2.x, a2.y}; X[5] = (v2f){a2.z, a2.w};
        X[6] = (v2f){a3.x, a3.y}; X[7] = (v2f){a3.z, a3.w};
    }

    __syncthreads();

    // ---------------- Phase 2: stream this wave's 8 rules -------------------
    float num = 0.0f, den = 0.0f;
    const float* rec0 = tab + wv * 8 * REC;    // wave-uniform

    #pragma unroll
    for (int rr = 0; rr < 8; ++rr) {
        const float* rec = rec0 + rr * REC;    // wave-uniform -> broadcasts

        v2f W = (v2f){1.0f, 1.0f};
        W *= memb_pair(X[0], rec, 0);
        W *= memb_pair(X[1], rec, 1);
        W *= memb_pair(X[2], rec, 2);
        W *= memb_pair(X[3], rec, 3);
        float w8 = W.x * W.y;
        if (__any(w8 != 0.0f)) {
            const float* recB = rec + 32;
            W *= memb_pair(X[4], recB, 0);
            W *= memb_pair(X[5], recB, 1);
            float w12 = W.x * W.y;
            if (__any(w12 != 0.0f)) {
                W *= memb_pair(X[6], recB, 2);
                W *= memb_pair(X[7], recB, 3);
                float wf = W.x * W.y;
                if (__any(wf != 0.0f)) {
                    v2f acc = (v2f){rec[80], 0.0f};      // bias
                    #pragma unroll
                    for (int p = 0; p < 8; ++p) {
                        v2f rh = *(const v2f*)(rec + 64 + 2 * p);
                        acc += X[p] * rh;                // v_pk_fma_f32
                    }
                    float z = acc.x + acc.y;
                    num = fmaf(z, wf, num);
                    den += wf;
                }
            }
        }
    }

    // ---------------- Phase 3: reduce across the 16 waves -------------------
    nsh[wv][lane] = num;
    dsh[wv][lane] = den;
    __syncthreads();

    if (t < 64) {
        float n = 0.0f, d = 0.0f;
        #pragma unroll
        for (int c = 0; c < 16; ++c) { n += nsh[c][t]; d += dsh[c][t]; }
        out[kbase + t] = n * __builtin_amdgcn_rcpf(d + 1e-13f);
    }
}

// ---------------------------------------------------------------------------
extern "C" void kernel_launch(void* const* d_in, const int* in_sizes, int n_in,
                              void* d_out, int out_size, void* d_ws, size_t ws_size,
                              hipStream_t stream) {
    const float* input = (const float*)d_in[0];   // (K, A)    fp32
    const float* abcd  = (const float*)d_in[1];   // (R, A, 4) fp32
    const float* rho   = (const float*)d_in[2];   // (R, A+1)  fp32
    float* out = (float*)d_out;                   // (K,)      fp32

    fuzzy_fused<<<K_TOTAL / 64, 1024, 0, stream>>>(input, abcd, rho, out);
}

// Round 10
// 13.096 us; speedup vs baseline: 2.3016x; 1.0322x over previous
//
#include <hip/hip_runtime.h>

#define K_TOTAL 32768
#define R_TOTAL 128
#define A_DIM   16
#define KB      128      // k-points per block (2 per lane)

#define REC 84   // floats per rule record in LDS (336 B)
// per-rule LDS record layout (floats):
//   [ 0..31]  stage A (dims 0-7):  IBA[8] | C1[8]=-A*IBA | NIDC[8]=-IDC | C3[8]=D*IDC
//   [32..63]  stage B (dims 8-15): same sub-layout
//   [64..79]  rho[0..15]
//   [80]      bias ; [81..83] pad

typedef float v2f __attribute__((ext_vector_type(2)));

// membership for one dim-pair applied to TWO k-points: constants are read
// from LDS once and reused -> LDS broadcast bytes per k halve.
__device__ __forceinline__ void memb_pair2(v2f Xa, v2f Xb, const float* rec, int p,
                                           v2f& Wa, v2f& Wb) {
    v2f iba = *(const v2f*)(rec + 2 * p);
    v2f c1  = *(const v2f*)(rec + 8 + 2 * p);
    v2f nid = *(const v2f*)(rec + 16 + 2 * p);
    v2f c3  = *(const v2f*)(rec + 24 + 2 * p);
    v2f ra = Xa * iba + c1;      // v_pk_fma_f32
    v2f fa = Xa * nid + c3;
    v2f rb = Xb * iba + c1;
    v2f fb = Xb * nid + c3;
    v2f Ma, Mb;
    Ma.x = __builtin_amdgcn_fmed3f(fminf(ra.x, fa.x), 0.0f, 1.0f);
    Ma.y = __builtin_amdgcn_fmed3f(fminf(ra.y, fa.y), 0.0f, 1.0f);
    Mb.x = __builtin_amdgcn_fmed3f(fminf(rb.x, fb.x), 0.0f, 1.0f);
    Mb.y = __builtin_amdgcn_fmed3f(fminf(rb.y, fb.y), 0.0f, 1.0f);
    Wa *= Ma;
    Wb *= Mb;
}

// Single fused kernel. 256 blocks x 1024 threads (16 waves). Block owns 128
// k's: lane carries k = kbase+lane and k = kbase+64+lane. Wave wv owns rules
// [wv*8, wv*8+8). Phase 1: block folds sort+rcp constants into LDS once.
// Phase 2: wave-uniform LDS broadcasts feed packed-fp32 VALU for both
// k-instances; early-out after dims 8 / 12; z-dot only when some lane
// survives all 16 dims. Skips are exact +0 => matches reference support.
__global__ __launch_bounds__(1024, 4)
void fuzzy_fused(const float* __restrict__ input,
                 const float* __restrict__ abcd,
                 const float* __restrict__ rho,
                 float* __restrict__ out) {
    __shared__ float tab[R_TOTAL * REC];   // 43008 B
    __shared__ float nsh[16][KB];          // 8192 B
    __shared__ float dsh[16][KB];          // 8192 B

    const int t     = threadIdx.x;
    const int lane  = t & 63;
    const int wv    = __builtin_amdgcn_readfirstlane(t >> 6);
    const int kbase = blockIdx.x * KB;

    // ---------------- Phase 1: fold constants into LDS ---------------------
    #pragma unroll
    for (int i = 0; i < 2; ++i) {
        int e  = t + i * 1024;                 // (r,a) entry, < 2048
        int r  = e >> 4, a = e & 15, st = a >> 3, ai = a & 7;
        float4 v = ((const float4*)abcd)[e];
        float v0 = v.x, v1 = v.y, v2 = v.z, v3 = v.w, s;
        s = fminf(v0, v1); v1 = fmaxf(v0, v1); v0 = s;
        s = fminf(v2, v3); v3 = fmaxf(v2, v3); v2 = s;
        s = fminf(v0, v2); v2 = fmaxf(v0, v2); v0 = s;
        s = fminf(v1, v3); v3 = fmaxf(v1, v3); v1 = s;
        s = fminf(v1, v2); v2 = fmaxf(v1, v2); v1 = s;
        // v0<=v1<=v2<=v3
        float iba = __builtin_amdgcn_rcpf(v1 - v0);
        float idc = __builtin_amdgcn_rcpf(v3 - v2);
        float* base = tab + r * REC + st * 32;
        base[ai]      =  iba;
        base[8 + ai]  = -v0 * iba;
        base[16 + ai] = -idc;
        base[24 + ai] =  v3 * idc;
    }
    #pragma unroll
    for (int i = 0; i < 3; ++i) {
        int f = t + i * 1024;                  // rho element, < 2176
        if (f < R_TOTAL * (A_DIM + 1)) {
            int r = f / (A_DIM + 1);
            int c = f - r * (A_DIM + 1);
            tab[r * REC + 64 + c] = rho[f];    // c==16 -> bias at [80]
        }
    }

    // per-lane coordinates for the two k-instances (overlaps fold latency)
    v2f Xa[8], Xb[8];
    {
        const float4* xp = (const float4*)(input + (size_t)(kbase + lane) * A_DIM);
        float4 a0 = xp[0], a1 = xp[1], a2 = xp[2], a3 = xp[3];
        Xa[0] = (v2f){a0.x, a0.y}; Xa[1] = (v2f){a0.z, a0.w};
        Xa[2] = (v2f){a1.x, a1.y}; Xa[3] = (v2f){a1.z, a1.w};
        Xa[4] = (v2f){a2.x, a2.y}; Xa[5] = (v2f){a2.z, a2.w};
        Xa[6] = (v2f){a3.x, a3.y}; Xa[7] = (v2f){a3.z, a3.w};
        const float4* yp = (const float4*)(input + (size_t)(kbase + 64 + lane) * A_DIM);
        float4 b0 = yp[0], b1 = yp[1], b2 = yp[2], b3 = yp[3];
        Xb[0] = (v2f){b0.x, b0.y}; Xb[1] = (v2f){b0.z, b0.w};
        Xb[2] = (v2f){b1.x, b1.y}; Xb[3] = (v2f){b1.z, b1.w};
        Xb[4] = (v2f){b2.x, b2.y}; Xb[5] = (v2f){b2.z, b2.w};
        Xb[6] = (v2f){b3.x, b3.y}; Xb[7] = (v2f){b3.z, b3.w};
    }

    __syncthreads();

    // ---------------- Phase 2: stream this wave's 8 rules -------------------
    float numA = 0.0f, denA = 0.0f, numB = 0.0f, denB = 0.0f;
    const float* rec0 = tab + wv * 8 * REC;    // wave-uniform

    #pragma unroll
    for (int rr = 0; rr < 8; ++rr) {
        const float* rec = rec0 + rr * REC;    // wave-uniform -> broadcasts

        v2f Wa = (v2f){1.0f, 1.0f}, Wb = (v2f){1.0f, 1.0f};
        memb_pair2(Xa[0], Xb[0], rec, 0, Wa, Wb);
        memb_pair2(Xa[1], Xb[1], rec, 1, Wa, Wb);
        memb_pair2(Xa[2], Xb[2], rec, 2, Wa, Wb);
        memb_pair2(Xa[3], Xb[3], rec, 3, Wa, Wb);
        float w8a = Wa.x * Wa.y, w8b = Wb.x * Wb.y;
        if (__any((w8a != 0.0f) | (w8b != 0.0f))) {
            const float* recB = rec + 32;
            memb_pair2(Xa[4], Xb[4], recB, 0, Wa, Wb);
            memb_pair2(Xa[5], Xb[5], recB, 1, Wa, Wb);
            float w12a = Wa.x * Wa.y, w12b = Wb.x * Wb.y;
            if (__any((w12a != 0.0f) | (w12b != 0.0f))) {
                memb_pair2(Xa[6], Xb[6], recB, 2, Wa, Wb);
                memb_pair2(Xa[7], Xb[7], recB, 3, Wa, Wb);
                float wfa = Wa.x * Wa.y, wfb = Wb.x * Wb.y;
                if (__any((wfa != 0.0f) | (wfb != 0.0f))) {
                    v2f accA = (v2f){rec[80], 0.0f};     // bias
                    v2f accB = (v2f){rec[80], 0.0f};
                    #pragma unroll
                    for (int p = 0; p < 8; ++p) {
                        v2f rh = *(const v2f*)(rec + 64 + 2 * p);
                        accA += Xa[p] * rh;              // v_pk_fma_f32
                        accB += Xb[p] * rh;
                    }
                    float za = accA.x + accA.y;
                    float zb = accB.x + accB.y;
                    numA = fmaf(za, wfa, numA);  denA += wfa;
                    numB = fmaf(zb, wfb, numB);  denB += wfb;
                }
            }
        }
    }

    // ---------------- Phase 3: reduce across the 16 waves -------------------
    nsh[wv][lane]      = numA;
    dsh[wv][lane]      = denA;
    nsh[wv][64 + lane] = numB;
    dsh[wv][64 + lane] = denB;
    __syncthreads();

    if (t < KB) {
        float n = 0.0f, d = 0.0f;
        #pragma unroll
        for (int c = 0; c < 16; ++c) { n += nsh[c][t]; d += dsh[c][t]; }
        out[kbase + t] = n * __builtin_amdgcn_rcpf(d + 1e-13f);
    }
}

// ---------------------------------------------------------------------------
extern "C" void kernel_launch(void* const* d_in, const int* in_sizes, int n_in,
                              void* d_out, int out_size, void* d_ws, size_t ws_size,
                              hipStream_t stream) {
    const float* input = (const float*)d_in[0];   // (K, A)    fp32
    const float* abcd  = (const float*)d_in[1];   // (R, A, 4) fp32
    const float* rho   = (const float*)d_in[2];   // (R, A+1)  fp32
    float* out = (float*)d_out;                   // (K,)      fp32

    fuzzy_fused<<<K_TOTAL / KB, 1024, 0, stream>>>(input, abcd, rho, out);
}